// Round 1
// baseline (145.085 us; speedup 1.0000x reference)
//
#include <hip/hip_runtime.h>
#include <stdint.h>

// AdaMoLE fused pipeline, bf16 MFMA.
//  N=8192 tokens, D_IN=4096, D_OUT=4096, E=8, r=16, SCALING=2.0, MAX_THR=1/8.
//
//  ws layout:
//    W1  : bf16, chunked [kc=64][row=144][k'=64], XOR-swizzled within 128B rows (1,179,648 B)
//    B2T : bf16, [o=4096][k=128], k=e*16+r, value = lora_B[e][o][r]*2.0      (1,048,576 B)
//    wh  : bf16, [n=8192][c=128], weighted h                                  (2,097,152 B)

typedef __bf16 bf16x8 __attribute__((ext_vector_type(8)));
typedef float f32x4 __attribute__((ext_vector_type(4)));

__device__ __forceinline__ f32x4 mfma16(bf16x8 a, bf16x8 b, f32x4 c) {
  return __builtin_amdgcn_mfma_f32_16x16x32_bf16(a, b, c, 0, 0, 0);
}

// fp32 -> bf16 bits, round-to-nearest-even
__device__ __forceinline__ uint32_t bfbits(float f) {
  uint32_t u = __builtin_bit_cast(uint32_t, f);
  return (u + 0x7fffu + ((u >> 16) & 1u)) >> 16;
}

// ---------------- pack W1: rows 0..127 = lora_A (row = e*16+r), 128..135 = router_w,
// 136 = thr_w, 137..143 = zero pad. Stored per 64-wide K chunk, 128B rows,
// byte-offset XOR-swizzled by ((row&7)<<4) so kernel-1 can stage LDS linearly.
__global__ void pack_w1(const float* __restrict__ router_w,
                        const float* __restrict__ thr_w,
                        const float* __restrict__ lora_A,
                        uint32_t* __restrict__ W1) {
  int id = blockIdx.x * 256 + threadIdx.x;   // 64*144*32 threads
  int kp  = id & 31;                         // bf16 pair within chunk row
  int row = (id >> 5) % 144;
  int kc  = id / (32 * 144);
  int k   = kc * 64 + kp * 2;
  float v0 = 0.f, v1 = 0.f;
  if (row < 137) {
    const float* src = (row < 128) ? lora_A + (size_t)row * 4096
                     : (row < 136) ? router_w + (size_t)(row - 128) * 4096
                                   : thr_w;
    v0 = src[k]; v1 = src[k + 1];
  }
  uint32_t val = bfbits(v0) | (bfbits(v1) << 16);
  W1[(size_t)(kc * 144 + row) * 32 + (kp ^ ((row & 7) << 2))] = val;
}

// ---------------- pack B2T[o][k] = lora_B[e][o][r] * 2.0 (SCALING folded), bf16
__global__ void pack_b2(const float* __restrict__ lora_B, uint32_t* __restrict__ B2) {
  int id = blockIdx.x * 256 + threadIdx.x;   // 4096*64 threads
  int kp = id & 63;
  int o  = id >> 6;
  int k  = kp * 2;
  int e = k >> 4, r = k & 15;                // k even -> r<=14, pair stays in-expert
  const float* s = lora_B + (size_t)e * 4096 * 16 + (size_t)o * 16 + r;
  uint32_t val = bfbits(s[0] * 2.0f) | (bfbits(s[1] * 2.0f) << 16);
  B2[(size_t)o * 64 + kp] = val;
}

// ---------------- kernel 1: gating + h, fused. 32 tokens/block, 8 waves.
// C tile = [32 tok][144 cols]: cols 0..127 = h (expert e = col>>4), 128..135 = router
// logits, 136 = thr logit. Wave w: m = w>>2 (token half), q = w&3: tiles
// q0{0,1} q1{2,3} q2{4,5} q3{6,7,8}; tile 8 carries the gating columns.
__global__ __launch_bounds__(512) void k1_gate_h(
    const float* __restrict__ inp, const uint4* __restrict__ W1,
    const float* __restrict__ rb, const float* __restrict__ tb,
    unsigned short* __restrict__ wh) {
  __shared__ __align__(16) unsigned short Al[2][32 * 64];
  __shared__ __align__(16) unsigned short Wl[2][144 * 64];
  __shared__ float scores[32][16];
  __shared__ float wgt[32][8];
  __shared__ __align__(16) unsigned short whl[32 * 128];

  const int t = threadIdx.x;
  const int lane = t & 63;
  const int wave = t >> 6;
  const int m = wave >> 2;
  const int q = wave & 3;
  const int n0 = blockIdx.x * 32;
  const int nt_cnt = (q == 3) ? 3 : 2;
  const int t0 = q * 2;

  f32x4 acc[3] = {{0.f,0.f,0.f,0.f},{0.f,0.f,0.f,0.f},{0.f,0.f,0.f,0.f}};

  // A staging assignment: 512 threads x 4 floats = 32 rows x 64 k
  const int arow = t >> 4;
  const int ac4  = (t & 15) * 4;
  const float* aptr = inp + (size_t)(n0 + arow) * 4096 + ac4;
  const int aoff = arow * 128 + ((ac4 * 2) ^ ((arow & 7) << 4)); // swizzled dest bytes

  // fragment read bases
  const int ar   = m * 16 + (lane & 15);
  const int abase = ar * 128;
  const int aswz  = (ar & 7) << 4;
  const int lswz  = (lane & 7) << 4;   // == (wr&7)<<4 for any 16-aligned tile base

  // ---- prologue: stage chunk 0 into buf 0
  {
    float4 av = *(const float4*)(aptr);
    uint4 w0 = W1[t];
    uint4 w1 = W1[t + 512];
    uint4 w2; if (t < 128) w2 = W1[t + 1024];
    uint2 a2;
    a2.x = bfbits(av.x) | (bfbits(av.y) << 16);
    a2.y = bfbits(av.z) | (bfbits(av.w) << 16);
    *(uint2*)((char*)Al[0] + aoff) = a2;
    uint4* wl = (uint4*)Wl[0];
    wl[t] = w0; wl[t + 512] = w1; if (t < 128) wl[t + 1024] = w2;
  }
  __syncthreads();

  for (int kc = 0; kc < 64; ++kc) {
    const int buf = kc & 1;
    const bool pre = (kc + 1 < 64);
    float4 av; uint4 w0, w1, w2;
    if (pre) {  // issue next-chunk global loads before compute (latency overlap)
      av = *(const float4*)(aptr + (size_t)(kc + 1) * 64);
      const uint4* wc = W1 + (size_t)(kc + 1) * 1152;
      w0 = wc[t]; w1 = wc[t + 512];
      if (t < 128) w2 = wc[t + 1024];
    }
    const char* Ab = (const char*)Al[buf];
    const char* Wb = (const char*)Wl[buf];
#pragma unroll
    for (int ks = 0; ks < 2; ++ks) {
      const int koffb = ks * 64 + (lane >> 4) * 16;
      bf16x8 a = *(const bf16x8*)(Ab + abase + (koffb ^ aswz));
#pragma unroll
      for (int i = 0; i < 3; ++i) {
        if (i < nt_cnt) {
          const int wr = (t0 + i) * 16 + (lane & 15);
          bf16x8 b = *(const bf16x8*)(Wb + wr * 128 + (koffb ^ lswz));
          acc[i] = mfma16(a, b, acc[i]);
        }
      }
    }
    if (pre) {
      const int nb = buf ^ 1;
      uint2 a2;
      a2.x = bfbits(av.x) | (bfbits(av.y) << 16);
      a2.y = bfbits(av.z) | (bfbits(av.w) << 16);
      *(uint2*)((char*)Al[nb] + aoff) = a2;
      uint4* wl = (uint4*)Wl[nb];
      wl[t] = w0; wl[t + 512] = w1; if (t < 128) wl[t + 1024] = w2;
    }
    __syncthreads();
  }

  // ---- epilogue: gating
  if (q == 3) {  // tile index 2 == global tile 8 (cols 128..143)
#pragma unroll
    for (int r = 0; r < 4; ++r) {
      const int tok = m * 16 + (lane >> 4) * 4 + r;
      scores[tok][lane & 15] = acc[2][r];
    }
  }
  __syncthreads();
  if (t < 32) {
    float l[9];
#pragma unroll
    for (int e = 0; e < 9; ++e) l[e] = scores[t][e];
    float mx = -3.4e38f;
#pragma unroll
    for (int e = 0; e < 8; ++e) { l[e] += rb[e]; mx = fmaxf(mx, l[e]); }
    float g[8], s = 0.f;
#pragma unroll
    for (int e = 0; e < 8; ++e) { g[e] = __expf(l[e] - mx); s += g[e]; }
    const float lt  = l[8] + tb[0];
    const float thr = 0.125f / (1.f + __expf(-lt));     // sigmoid * MAX_THRESHOLD
    const float inv = 1.f / s;
    float w[8], ws = 0.f;
#pragma unroll
    for (int e = 0; e < 8; ++e) { w[e] = fmaxf(g[e] * inv - thr, 0.f); ws += w[e]; }
    const float wn = (ws == 0.f) ? 1.f : ws;
#pragma unroll
    for (int e = 0; e < 8; ++e) wgt[t][e] = w[e] / wn;
  }
  __syncthreads();

  // weighted h -> LDS bounce (bf16), tiles with cols<128 only
#pragma unroll
  for (int i = 0; i < 2; ++i) {
    const int gt  = t0 + i;                 // global tile == expert index
    const int col = gt * 16 + (lane & 15);
#pragma unroll
    for (int r = 0; r < 4; ++r) {
      const int tok = m * 16 + (lane >> 4) * 4 + r;
      whl[tok * 128 + col] = (unsigned short)bfbits(acc[i][r] * wgt[tok][gt]);
    }
  }
  __syncthreads();
  {  // coalesced wh write: 32 rows x 16 uint4
    const int row = t >> 4, seg = t & 15;
    ((uint4*)(wh + (size_t)(n0 + row) * 128))[seg] =
        ((const uint4*)(whl + row * 128))[seg];
  }
}

// ---------------- kernel 2: out = wh @ B2T (K=128), write-bound. No LDS.
__global__ __launch_bounds__(256) void k2_out(
    const unsigned short* __restrict__ wh,
    const unsigned short* __restrict__ B2,
    float* __restrict__ out) {
  const int t = threadIdx.x;
  const int lane = t & 63;
  const int wave = t >> 6;
  const int bid = blockIdx.x;
  const int tok0 = (bid >> 6) * 64 + wave * 16;
  const int col0 = (bid & 63) * 64;
  f32x4 acc[4] = {{0.f,0.f,0.f,0.f},{0.f,0.f,0.f,0.f},{0.f,0.f,0.f,0.f},{0.f,0.f,0.f,0.f}};
  const uint4* Ar = (const uint4*)(wh + (size_t)(tok0 + (lane & 15)) * 128);
  const int kq = lane >> 4;
#pragma unroll
  for (int ks = 0; ks < 4; ++ks) {
    bf16x8 a = __builtin_bit_cast(bf16x8, Ar[ks * 4 + kq]);
#pragma unroll
    for (int nt = 0; nt < 4; ++nt) {
      const uint4* Br = (const uint4*)(B2 + (size_t)(col0 + nt * 16 + (lane & 15)) * 128);
      bf16x8 b = __builtin_bit_cast(bf16x8, Br[ks * 4 + kq]);
      acc[nt] = mfma16(a, b, acc[nt]);
    }
  }
  const int r0 = (lane >> 4) * 4;
#pragma unroll
  for (int nt = 0; nt < 4; ++nt) {
#pragma unroll
    for (int r = 0; r < 4; ++r) {
      out[(size_t)(tok0 + r0 + r) * 4096 + col0 + nt * 16 + (lane & 15)] = acc[nt][r];
    }
  }
}

extern "C" void kernel_launch(void* const* d_in, const int* in_sizes, int n_in,
                              void* d_out, int out_size, void* d_ws, size_t ws_size,
                              hipStream_t stream) {
  (void)in_sizes; (void)n_in; (void)out_size; (void)ws_size;
  const float* inp      = (const float*)d_in[0];
  const float* router_w = (const float*)d_in[1];
  const float* router_b = (const float*)d_in[2];
  const float* thr_w    = (const float*)d_in[3];
  const float* thr_b    = (const float*)d_in[4];
  const float* lora_A   = (const float*)d_in[5];
  const float* lora_B   = (const float*)d_in[6];
  float* out = (float*)d_out;

  char* ws = (char*)d_ws;
  uint32_t*       W1 = (uint32_t*)ws;                              // 1,179,648 B
  unsigned short* B2 = (unsigned short*)(ws + 1179648);            // 1,048,576 B
  unsigned short* wh = (unsigned short*)(ws + 1179648 + 1048576);  // 2,097,152 B

  pack_w1<<<1152, 256, 0, stream>>>(router_w, thr_w, lora_A, W1);
  pack_b2<<<1024, 256, 0, stream>>>(lora_B, (uint32_t*)B2);
  k1_gate_h<<<256, 512, 0, stream>>>(inp, (const uint4*)W1, router_b, thr_b, wh);
  k2_out<<<8192, 256, 0, stream>>>(wh, B2, out);
}